// Round 2
// baseline (89.596 us; speedup 1.0000x reference)
//
#include <hip/hip_runtime.h>

#define NB 8
#define LC 512
#define LQ 64
#define DD 256
#define NEG_BIG_F 1e30f

#define TPB 512           // threads per block (8 waves)
#define RPW 2             // rows per wave
#define RPB 16            // rows per block = 8 waves * RPW
#define BPB (LC / RPB)    // blocks per batch = 32

// Broadcast a float from `lane` to all lanes as a wave-uniform (SGPR) value.
__device__ __forceinline__ float bcastf(float x, int lane) {
  return __uint_as_float((unsigned)__builtin_amdgcn_readlane((int)__float_as_uint(x), lane));
}

__global__ __launch_bounds__(TPB) void rows_kernel(
    const float* __restrict__ context,   // [NB][LC][DD]
    const float* __restrict__ question,  // [NB][LQ][DD]
    const int*   __restrict__ mask,      // [NB][LQ]
    const float* __restrict__ att_w,     // [3*DD]
    const float* __restrict__ att_b,     // [1]
    const float* __restrict__ w_in,      // [DD]
    const float* __restrict__ w_mem,     // [DD]
    float* __restrict__ out,             // [NB][LC][4]
    float* __restrict__ ws)              // m[NB*LC], c1[NB*LC], U[NB*LC]
{
  // qs4[c][j] = question[b][j][4c..4c+3]  (lane j reads qs4[c][j] ->
  // consecutive 16B per lane -> canonical conflict-free ds_read_b128)
  __shared__ float4 qs4[64][64];                 // 64 KiB
  __shared__ float sq_part[LQ][8];
  __shared__ float q1_part[LQ][8];
  __shared__ float sqm[LQ];
  __shared__ float q1s[LQ];

  const int tid  = threadIdx.x;
  const int b    = blockIdx.x / BPB;
  const int row0 = (blockIdx.x % BPB) * RPB;

  // ---- pre-phase: stage question[b] into LDS, compute sq[j]+bias+mask, q1[j]
  {
    const int j  = tid >> 3;       // 0..63
    const int dq = tid & 7;        // d-range [dq*32, dq*32+32)
    const float4* qrow = (const float4*)(question + ((size_t)b * LQ + j) * DD + dq * 32);
    const float4* wq   = (const float4*)(att_w + DD + dq * 32);
    const float4* wm   = (const float4*)(w_mem + dq * 32);
    float psq = 0.f, pq1 = 0.f;
#pragma unroll
    for (int k = 0; k < 8; ++k) {
      float4 v = qrow[k];
      float4 a = wq[k];
      float4 c = wm[k];
      psq += v.x*a.x + v.y*a.y + v.z*a.z + v.w*a.w;
      pq1 += v.x*c.x + v.y*c.y + v.z*c.z + v.w*c.w;
      qs4[dq*8 + k][j] = v;        // d-offset = dq*32+4k = 4*(dq*8+k)  ✓
    }
    sq_part[j][dq] = psq;
    q1_part[j][dq] = pq1;
  }
  __syncthreads();
  if (tid < LQ) {
    const int j = tid;
    float sq = att_b[0];
    float q1 = 0.f;
#pragma unroll
    for (int k = 0; k < 8; ++k) { sq += sq_part[j][k]; q1 += q1_part[j][k]; }
    float mf = (float)mask[b * LQ + j];
    sqm[j] = sq - NEG_BIG_F * (1.0f - mf);
    q1s[j] = q1;
  }
  __syncthreads();

  // ---- main phase: wave w handles rows i0..i0+RPW-1, lane l = column j
  const int w  = tid >> 6;            // 0..7
  const int l  = tid & 63;
  const int i0 = row0 + w * RPW;

  const float4 wc4 = ((const float4*)att_w)[l];
  const float4 wp4 = ((const float4*)(att_w + 2 * DD))[l];
  const float4 wi4 = ((const float4*)w_in)[l];

  float4 cp[RPW];
  float sc[RPW], c1[RPW];
#pragma unroll
  for (int r = 0; r < RPW; ++r) {
    float4 c4 = ((const float4*)(context + ((size_t)b * LC + i0 + r) * DD))[l];
    sc[r] = c4.x*wc4.x + c4.y*wc4.y + c4.z*wc4.z + c4.w*wc4.w;
    c1[r] = c4.x*wi4.x + c4.y*wi4.y + c4.z*wi4.z + c4.w*wi4.w;
    cp[r].x = c4.x*wp4.x; cp[r].y = c4.y*wp4.y; cp[r].z = c4.z*wp4.z; cp[r].w = c4.w*wp4.w;
  }
  // wave-reduce sc (scores' context term) and c1 (ctx1) for each row
#pragma unroll
  for (int off = 32; off > 0; off >>= 1) {
#pragma unroll
    for (int r = 0; r < RPW; ++r) {
      sc[r] += __shfl_xor(sc[r], off);
      c1[r] += __shfl_xor(c1[r], off);
    }
  }

  // sp[i_r][j]: lane j accumulates over d; ctx broadcast from lane c via
  // readlane (full unroll -> immediate lane operands, no SGPR setup)
  float acc[RPW] = {0.f, 0.f};
#pragma unroll
  for (int c = 0; c < 64; ++c) {
    float4 qv = qs4[c][l];
#pragma unroll
    for (int r = 0; r < RPW; ++r) {
      acc[r] += bcastf(cp[r].x, c) * qv.x
              + bcastf(cp[r].y, c) * qv.y
              + bcastf(cp[r].z, c) * qv.z
              + bcastf(cp[r].w, c) * qv.w;
    }
  }

  const float sqm_l = sqm[l];
  const float q1_l  = q1s[l];
#pragma unroll
  for (int r = 0; r < RPW; ++r) {
    float v = acc[r] + sc[r] + sqm_l;     // masked attention score, lane = j
    float m = v;
#pragma unroll
    for (int off = 32; off > 0; off >>= 1) m = fmaxf(m, __shfl_xor(m, off));
    float p  = __expf(v - m);
    float ps = p;
    float pu = p * q1_l;
#pragma unroll
    for (int off = 32; off > 0; off >>= 1) {
      ps += __shfl_xor(ps, off);
      pu += __shfl_xor(pu, off);
    }
    if (l == 0) {
      const int gi = b * LC + i0 + r;
      const float U = pu / ps;
      out[gi * 4 + 0] = c1[r];
      out[gi * 4 + 1] = U;
      out[gi * 4 + 2] = c1[r] * U;
      ws[gi]               = m;      // row max of masked scores
      ws[NB * LC + gi]     = c1[r];  // ctx1
      ws[2 * NB * LC + gi] = U;
    }
  }
}

__global__ __launch_bounds__(512) void batch_kernel(
    const float* __restrict__ ws,
    float* __restrict__ out)
{
  const int b = blockIdx.x;
  const int t = threadIdx.x;          // t = row i (512 threads)
  const int gi = b * LC + t;
  const float m  = ws[gi];
  const float c1 = ws[NB * LC + gi];
  const float U  = ws[2 * NB * LC + gi];

  const int w = t >> 6, l = t & 63;
  __shared__ float rmax[8], rs[8], rc[8];

  float mx = m;
#pragma unroll
  for (int off = 32; off > 0; off >>= 1) mx = fmaxf(mx, __shfl_xor(mx, off));
  if (l == 0) rmax[w] = mx;
  __syncthreads();
  mx = rmax[0];
#pragma unroll
  for (int k = 1; k < 8; ++k) mx = fmaxf(mx, rmax[k]);

  float p  = __expf(m - mx);
  float ps = p;
  float pc = p * c1;
#pragma unroll
  for (int off = 32; off > 0; off >>= 1) {
    ps += __shfl_xor(ps, off);
    pc += __shfl_xor(pc, off);
  }
  if (l == 0) { rs[w] = ps; rc[w] = pc; }
  __syncthreads();
  float S = 0.f, C = 0.f;
#pragma unroll
  for (int k = 0; k < 8; ++k) { S += rs[k]; C += rc[k]; }

  const float H = C / S;
  out[gi * 4 + 3] = U * H;
}

extern "C" void kernel_launch(void* const* d_in, const int* in_sizes, int n_in,
                              void* d_out, int out_size, void* d_ws, size_t ws_size,
                              hipStream_t stream) {
  const float* context  = (const float*)d_in[0];
  const float* question = (const float*)d_in[1];
  const int*   mask     = (const int*)d_in[2];
  const float* att_w    = (const float*)d_in[3];
  const float* att_b    = (const float*)d_in[4];
  const float* w_in     = (const float*)d_in[5];
  const float* w_mem    = (const float*)d_in[6];
  float* out = (float*)d_out;
  float* ws  = (float*)d_ws;

  rows_kernel<<<dim3(NB * BPB), dim3(TPB), 0, stream>>>(
      context, question, mask, att_w, att_b, w_in, w_mem, out, ws);
  batch_kernel<<<dim3(NB), dim3(512), 0, stream>>>(ws, out);
}

// Round 3
// 85.059 us; speedup vs baseline: 1.0533x; 1.0533x over previous
//
#include <hip/hip_runtime.h>

#define NB 8
#define LC 512
#define LQ 64
#define DD 256
#define NEG_BIG_F 1e30f

#define TPB 256           // 4 waves
#define NWAVE 4
#define RPW 4             // rows per wave
#define RPB 16            // rows per block
#define BPB (LC / RPB)    // blocks per batch = 32

// Broadcast a float from `lane` to all lanes as a wave-uniform (SGPR) value.
__device__ __forceinline__ float bcastf(float x, int lane) {
  return __uint_as_float((unsigned)__builtin_amdgcn_readlane((int)__float_as_uint(x), lane));
}

__global__ __launch_bounds__(TPB) void rows_kernel(
    const float* __restrict__ context,   // [NB][LC][DD]
    const float* __restrict__ question,  // [NB][LQ][DD]
    const int*   __restrict__ mask,      // [NB][LQ]
    const float* __restrict__ att_w,     // [3*DD]
    const float* __restrict__ att_b,     // [1]
    const float* __restrict__ w_in,      // [DD]
    const float* __restrict__ w_mem,     // [DD]
    float4* __restrict__ ws4)            // [NB*LC] {rowmax, ctx1, U, 0}
{
  // qs4[c][j] = question[b][j][4c..4c+3]; lane j accesses qs4[c][j] ->
  // consecutive 16B per lane -> conflict-free ds_read/write_b128.
  __shared__ float4 qs4[64][64];                 // 64 KiB
  __shared__ float sq_part[LQ][NWAVE + 1];       // +1 pad: conflict-free
  __shared__ float q1_part[LQ][NWAVE + 1];
  __shared__ float sqm[LQ];
  __shared__ float q1s[LQ];

  const int tid  = threadIdx.x;
  const int w    = tid >> 6;          // wave 0..3
  const int l    = tid & 63;          // lane
  const int b    = blockIdx.x / BPB;
  const int row0 = (blockIdx.x % BPB) * RPB;
  const int i0   = row0 + w * RPW;

  // ---- hoisted global loads (overlap HBM latency with staging) ----
  const float4 wc4 = ((const float4*)att_w)[l];
  const float4 wp4 = ((const float4*)(att_w + 2 * DD))[l];
  const float4 wi4 = ((const float4*)w_in)[l];
  float4 c4r[RPW];
#pragma unroll
  for (int r = 0; r < RPW; ++r)
    c4r[r] = ((const float4*)(context + ((size_t)b * LC + i0 + r) * DD))[l];

  // ---- staging: wave w stages d-chunk [w*64, w*64+64) for ALL 64 q-rows.
  // Lane l owns q-row l. LDS write qs4[w*16+k][l]: lane-consecutive 16B ->
  // conflict-free (fixes the 921600-conflict 8-way pattern of the old layout).
  {
    const float4* qrow = (const float4*)(question + ((size_t)b * LQ + l) * DD + w * 64);
    const float4* wqp  = (const float4*)(att_w + DD + w * 64);   // wave-uniform
    const float4* wmp  = (const float4*)(w_mem + w * 64);        // wave-uniform
    float psq = 0.f, pq1 = 0.f;
#pragma unroll
    for (int k = 0; k < 16; ++k) {
      float4 v = qrow[k];
      float4 a = wqp[k];
      float4 c = wmp[k];
      psq += v.x*a.x + v.y*a.y + v.z*a.z + v.w*a.w;
      pq1 += v.x*c.x + v.y*c.y + v.z*c.z + v.w*c.w;
      qs4[w * 16 + k][l] = v;   // d-offset = w*64+4k = 4*(w*16+k)  [ok]
    }
    sq_part[l][w] = psq;
    q1_part[l][w] = pq1;
  }
  __syncthreads();
  if (tid < LQ) {
    const int j = tid;
    float sq = att_b[0];
    float q1 = 0.f;
#pragma unroll
    for (int k = 0; k < NWAVE; ++k) { sq += sq_part[j][k]; q1 += q1_part[j][k]; }
    float mf = (float)mask[b * LQ + j];
    sqm[j] = sq - NEG_BIG_F * (1.0f - mf);
    q1s[j] = q1;
  }
  __syncthreads();

  // ---- main phase: wave w owns rows i0..i0+RPW-1; lane l = q-column j ----
  float4 cp[RPW];
  float sc[RPW], c1[RPW];
#pragma unroll
  for (int r = 0; r < RPW; ++r) {
    float4 c4 = c4r[r];
    sc[r] = c4.x*wc4.x + c4.y*wc4.y + c4.z*wc4.z + c4.w*wc4.w;
    c1[r] = c4.x*wi4.x + c4.y*wi4.y + c4.z*wi4.z + c4.w*wi4.w;
    cp[r].x = c4.x*wp4.x; cp[r].y = c4.y*wp4.y; cp[r].z = c4.z*wp4.z; cp[r].w = c4.w*wp4.w;
  }
  // wave-reduce sc (score context term) and c1 (ctx1) for each row
#pragma unroll
  for (int off = 32; off > 0; off >>= 1) {
#pragma unroll
    for (int r = 0; r < RPW; ++r) {
      sc[r] += __shfl_xor(sc[r], off);
      c1[r] += __shfl_xor(c1[r], off);
    }
  }

  // sp[i_r][j]: lane j accumulates over d; ctx broadcast from lane c via
  // readlane (full unroll -> immediate lane operands)
  float acc[RPW] = {0.f, 0.f, 0.f, 0.f};
#pragma unroll
  for (int c = 0; c < 64; ++c) {
    float4 qv = qs4[c][l];
#pragma unroll
    for (int r = 0; r < RPW; ++r) {
      acc[r] += bcastf(cp[r].x, c) * qv.x
              + bcastf(cp[r].y, c) * qv.y
              + bcastf(cp[r].z, c) * qv.z
              + bcastf(cp[r].w, c) * qv.w;
    }
  }

  const float sqm_l = sqm[l];
  const float q1_l  = q1s[l];
#pragma unroll
  for (int r = 0; r < RPW; ++r) {
    float v = acc[r] + sc[r] + sqm_l;     // masked attention score, lane = j
    float m = v;
#pragma unroll
    for (int off = 32; off > 0; off >>= 1) m = fmaxf(m, __shfl_xor(m, off));
    float p  = __expf(v - m);
    float ps = p;
    float pu = p * q1_l;
#pragma unroll
    for (int off = 32; off > 0; off >>= 1) {
      ps += __shfl_xor(ps, off);
      pu += __shfl_xor(pu, off);
    }
    if (l == 0) {
      const int gi = b * LC + i0 + r;
      ws4[gi] = make_float4(m, c1[r], pu / ps, 0.f);
    }
  }
}

__global__ __launch_bounds__(512) void batch_kernel(
    const float4* __restrict__ ws4,
    float4* __restrict__ out4)           // [NB*LC] {c1, U, c1*U, U*H}
{
  const int b  = blockIdx.x;
  const int t  = threadIdx.x;           // row i
  const int gi = b * LC + t;
  const float4 v = ws4[gi];
  const float m = v.x, c1 = v.y, U = v.z;

  const int w = t >> 6, l = t & 63;
  __shared__ float rmax[8], rs[8], rc[8];

  float mx = m;
#pragma unroll
  for (int off = 32; off > 0; off >>= 1) mx = fmaxf(mx, __shfl_xor(mx, off));
  if (l == 0) rmax[w] = mx;
  __syncthreads();
  mx = rmax[0];
#pragma unroll
  for (int k = 1; k < 8; ++k) mx = fmaxf(mx, rmax[k]);

  float p  = __expf(m - mx);
  float ps = p;
  float pc = p * c1;
#pragma unroll
  for (int off = 32; off > 0; off >>= 1) {
    ps += __shfl_xor(ps, off);
    pc += __shfl_xor(pc, off);
  }
  if (l == 0) { rs[w] = ps; rc[w] = pc; }
  __syncthreads();
  float S = 0.f, C = 0.f;
#pragma unroll
  for (int k = 0; k < 8; ++k) { S += rs[k]; C += rc[k]; }

  const float H = C / S;
  out4[gi] = make_float4(c1, U, c1 * U, U * H);
}

extern "C" void kernel_launch(void* const* d_in, const int* in_sizes, int n_in,
                              void* d_out, int out_size, void* d_ws, size_t ws_size,
                              hipStream_t stream) {
  const float* context  = (const float*)d_in[0];
  const float* question = (const float*)d_in[1];
  const int*   mask     = (const int*)d_in[2];
  const float* att_w    = (const float*)d_in[3];
  const float* att_b    = (const float*)d_in[4];
  const float* w_in     = (const float*)d_in[5];
  const float* w_mem    = (const float*)d_in[6];
  float4* out4 = (float4*)d_out;
  float4* ws4  = (float4*)d_ws;

  rows_kernel<<<dim3(NB * BPB), dim3(TPB), 0, stream>>>(
      context, question, mask, att_w, att_b, w_in, w_mem, ws4);
  batch_kernel<<<dim3(NB), dim3(512), 0, stream>>>(ws4, out4);
}

// Round 4
// 77.403 us; speedup vs baseline: 1.1575x; 1.0989x over previous
//
#include <hip/hip_runtime.h>

#define NB 8
#define LC 512
#define LQ 64
#define DD 256
#define NEG_BIG_F 1e30f

#define TPB 512           // 8 waves
#define NWAVE 8
#define RPB 8             // rows per block (1 per wave)
#define BPB (LC / RPB)    // blocks per batch = 64

// Broadcast a float from `lane` to all lanes as a wave-uniform (SGPR) value.
__device__ __forceinline__ float bcastf(float x, int lane) {
  return __uint_as_float((unsigned)__builtin_amdgcn_readlane((int)__float_as_uint(x), lane));
}

__global__ __launch_bounds__(TPB, 4) void rows_kernel(
    const float* __restrict__ context,   // [NB][LC][DD]
    const float* __restrict__ question,  // [NB][LQ][DD]
    const int*   __restrict__ mask,      // [NB][LQ]
    const float* __restrict__ att_w,     // [3*DD]
    const float* __restrict__ att_b,     // [1]
    const float* __restrict__ w_in,      // [DD]
    const float* __restrict__ w_mem,     // [DD]
    float4* __restrict__ ws4)            // [NB*LC] {rowmax, ctx1, U, 0}
{
  // T[c][j ^ (c&7)] = question[b][j][4c..4c+3].
  // Writes: lane=c (fixed j)  -> 8 distinct 16B slots per 128B phase.
  // Reads : lane=j (fixed c)  -> blockwise-XOR perm of consecutive float4s.
  // Both conflict-free.
  __shared__ float4 T[64][64];                   // 64 KiB
  __shared__ float sq_raw[LQ];                   // q-term of score (no bias/mask)
  __shared__ float q1_s[LQ];

  const int tid  = threadIdx.x;
  const int w    = tid >> 6;           // wave 0..7
  const int l    = tid & 63;           // lane
  const int b    = blockIdx.x / BPB;
  const int row0 = (blockIdx.x % BPB) * RPB;
  const int i    = row0 + w;           // this wave's context row

  // ---- hoisted per-lane loads (lane = d-chunk) ----
  const float4 wc4 = ((const float4*)att_w)[l];
  const float4 wq4 = ((const float4*)(att_w + DD))[l];
  const float4 wp4 = ((const float4*)(att_w + 2 * DD))[l];
  const float4 wi4 = ((const float4*)w_in)[l];
  const float4 wm4 = ((const float4*)w_mem)[l];
  const float4 c4  = ((const float4*)(context + ((size_t)b * LC + i) * DD))[l];

  // ---- staging: instruction k loads ONE full q-row (row j = k*8 + w):
  // 64 lanes x 16B = exactly the 1KiB row -> perfectly coalesced.
  float4 v[8];
#pragma unroll
  for (int k = 0; k < 8; ++k)
    v[k] = ((const float4*)(question + ((size_t)b * LQ + (k * 8 + w)) * DD))[l];
#pragma unroll
  for (int k = 0; k < 8; ++k)
    T[l][(k * 8 + w) ^ (l & 7)] = v[k];

  // per-row partial dot products (lane l holds chunk l's contribution)
  float psq[8], pq1[8];
#pragma unroll
  for (int k = 0; k < 8; ++k) {
    psq[k] = v[k].x*wq4.x + v[k].y*wq4.y + v[k].z*wq4.z + v[k].w*wq4.w;
    pq1[k] = v[k].x*wm4.x + v[k].y*wm4.y + v[k].z*wm4.z + v[k].w*wm4.w;
  }
  // butterfly-reduce all 16 chains together (ILP hides shuffle latency)
#pragma unroll
  for (int off = 32; off > 0; off >>= 1) {
#pragma unroll
    for (int k = 0; k < 8; ++k) {
      psq[k] += __shfl_xor(psq[k], off);
      pq1[k] += __shfl_xor(pq1[k], off);
    }
  }
  if (l == 0) {
#pragma unroll
    for (int k = 0; k < 8; ++k) {
      sq_raw[k * 8 + w] = psq[k];
      q1_s[k * 8 + w]   = pq1[k];
    }
  }

  // ---- this wave's row-local terms (overlap with staging latency) ----
  float4 cp;
  cp.x = c4.x*wp4.x; cp.y = c4.y*wp4.y; cp.z = c4.z*wp4.z; cp.w = c4.w*wp4.w;
  float sc = c4.x*wc4.x + c4.y*wc4.y + c4.z*wc4.z + c4.w*wc4.w;
  float c1 = c4.x*wi4.x + c4.y*wi4.y + c4.z*wi4.z + c4.w*wi4.w;
#pragma unroll
  for (int off = 32; off > 0; off >>= 1) {
    sc += __shfl_xor(sc, off);
    c1 += __shfl_xor(c1, off);
  }

  __syncthreads();

  // ---- main loop: lane l = q-column j; ctx chunk broadcast via readlane ----
  float a0 = 0.f, a1 = 0.f, a2 = 0.f, a3 = 0.f;   // 4 chains for ILP
#pragma unroll
  for (int c = 0; c < 64; ++c) {
    float4 qv = T[c][l ^ (c & 7)];
    a0 += bcastf(cp.x, c) * qv.x;
    a1 += bcastf(cp.y, c) * qv.y;
    a2 += bcastf(cp.z, c) * qv.z;
    a3 += bcastf(cp.w, c) * qv.w;
  }

  const float mf = (float)mask[b * LQ + l];
  const float vscore = (a0 + a1) + (a2 + a3) + sc + sq_raw[l] + att_b[0]
                       - NEG_BIG_F * (1.0f - mf);
  const float q1_l = q1_s[l];

  float m = vscore;
#pragma unroll
  for (int off = 32; off > 0; off >>= 1) m = fmaxf(m, __shfl_xor(m, off));
  float p  = __expf(vscore - m);
  float ps = p;
  float pu = p * q1_l;
#pragma unroll
  for (int off = 32; off > 0; off >>= 1) {
    ps += __shfl_xor(ps, off);
    pu += __shfl_xor(pu, off);
  }
  if (l == 0)
    ws4[b * LC + i] = make_float4(m, c1, pu / ps, 0.f);
}

__global__ __launch_bounds__(512) void batch_kernel(
    const float4* __restrict__ ws4,
    float4* __restrict__ out4)           // [NB*LC] {c1, U, c1*U, U*H}
{
  const int b  = blockIdx.x;
  const int t  = threadIdx.x;           // row i
  const int gi = b * LC + t;
  const float4 v = ws4[gi];
  const float m = v.x, c1 = v.y, U = v.z;

  const int w = t >> 6, l = t & 63;
  __shared__ float rmax[8], rs[8], rc[8];

  float mx = m;
#pragma unroll
  for (int off = 32; off > 0; off >>= 1) mx = fmaxf(mx, __shfl_xor(mx, off));
  if (l == 0) rmax[w] = mx;
  __syncthreads();
  mx = rmax[0];
#pragma unroll
  for (int k = 1; k < 8; ++k) mx = fmaxf(mx, rmax[k]);

  float p  = __expf(m - mx);
  float ps = p;
  float pc = p * c1;
#pragma unroll
  for (int off = 32; off > 0; off >>= 1) {
    ps += __shfl_xor(ps, off);
    pc += __shfl_xor(pc, off);
  }
  if (l == 0) { rs[w] = ps; rc[w] = pc; }
  __syncthreads();
  float S = 0.f, C = 0.f;
#pragma unroll
  for (int k = 0; k < 8; ++k) { S += rs[k]; C += rc[k]; }

  const float H = C / S;
  out4[gi] = make_float4(c1, U, c1 * U, U * H);
}

extern "C" void kernel_launch(void* const* d_in, const int* in_sizes, int n_in,
                              void* d_out, int out_size, void* d_ws, size_t ws_size,
                              hipStream_t stream) {
  const float* context  = (const float*)d_in[0];
  const float* question = (const float*)d_in[1];
  const int*   mask     = (const int*)d_in[2];
  const float* att_w    = (const float*)d_in[3];
  const float* att_b    = (const float*)d_in[4];
  const float* w_in     = (const float*)d_in[5];
  const float* w_mem    = (const float*)d_in[6];
  float4* out4 = (float4*)d_out;
  float4* ws4  = (float4*)d_ws;

  rows_kernel<<<dim3(NB * BPB), dim3(TPB), 0, stream>>>(
      context, question, mask, att_w, att_b, w_in, w_mem, ws4);
  batch_kernel<<<dim3(NB), dim3(512), 0, stream>>>(ws4, out4);
}